// Round 9
// baseline (164.455 us; speedup 1.0000x reference)
//
#include <hip/hip_runtime.h>

// out[(j*f + c)*m + q] = yd[idx[q*K + j]*f + c]
// m=8192, f=512, K=8, fp32. Memory-bound gather+transpose.
//
// Round 9 = Round 8 resubmit (round 8 was an infra failure, never ran).
// Intra-block software pipelining (persistent blocks, 4 tiles each).
// R2/R3/R6/R7 (store pattern, vectorization, occupancy, XCD affinity) were
// all null at 163us +- 2 -> the serialized per-tile phase chain
// (idx -> gather -> barrier -> LDS -> barrier -> store) is the last lever.
// Here the NEXT tile's idx+gather loads issue into registers during the
// CURRENT tile's LDS-read/store phase (issue-early/write-late), hiding the
// gather latency chain; rows[] LDS broadcast removed (direct idx loads,
// 8 lanes/address -> broadcast-coalesced).
//
// Geometry unchanged from R6/R7: tile = (j, CT=32 cols, QT=128 rows),
// 256 threads, lds[CT][132] (528B rows, b128-aligned), nt dwordx4 stores.

#define QT 128
#define CT 32
#define QPAD 132
#define THREADS 256
#define TPB 4

typedef float f32x4 __attribute__((ext_vector_type(4)));

__global__ __launch_bounds__(THREADS, 4) void gather_transpose_kernel(
    const float* __restrict__ yd, const int* __restrict__ idx,
    float* __restrict__ out, int m, int f, int k, int tiles_per_j)
{
    __shared__ float lds[CT][QPAD];
    const int t  = threadIdx.x;
    const int ch = t & 7;            // float4-chunk within a row's 32-col slice
    const int r0 = t >> 3;           // base row (0..31)
    const int gridP = gridDim.x;

    int tile = blockIdx.x;
    int j  = tile / tiles_per_j;
    int r  = tile - j * tiles_per_j;
    int cb = (r & 15) * CT;
    int qb = (r >> 4) * QT;

    // prologue: gather tile 0 into registers
    f32x4 d[4];
    #pragma unroll
    for (int l = 0; l < 4; ++l) {
        const int row = r0 + (l << 5);
        const int rr = idx[(size_t)(qb + row) * k + j];
        d[l] = *reinterpret_cast<const f32x4*>(
            yd + (size_t)rr * f + cb + (ch << 2));
    }

    #pragma unroll
    for (int it = 0; it < TPB; ++it) {
        __syncthreads();                       // prev tile's LDS readers done
        {
            const int c0 = ch << 2;
            #pragma unroll
            for (int l = 0; l < 4; ++l) {
                const int row = r0 + (l << 5);
                lds[c0 + 0][row] = d[l].x;
                lds[c0 + 1][row] = d[l].y;
                lds[c0 + 2][row] = d[l].z;
                lds[c0 + 3][row] = d[l].w;
            }
        }
        const int cur_cb = cb, cur_qb = qb, cur_j = j;

        // prefetch next tile into regs; latency hides under the store phase
        if (it + 1 < TPB) {
            tile += gridP;
            j  = tile / tiles_per_j;
            r  = tile - j * tiles_per_j;
            cb = (r & 15) * CT;
            qb = (r >> 4) * QT;
            #pragma unroll
            for (int l = 0; l < 4; ++l) {
                const int row = r0 + (l << 5);
                const int rr = idx[(size_t)(qb + row) * k + j];
                d[l] = *reinterpret_cast<const f32x4*>(
                    yd + (size_t)rr * f + cb + (ch << 2));
            }
        }

        __syncthreads();                       // lds writes visible
        const size_t outb = (size_t)cur_j * f * m + (size_t)cur_cb * m + cur_qb;
        #pragma unroll
        for (int l = 0; l < 4; ++l) {
            const int gid = l * THREADS + t;
            const int c  = gid >> 5;
            const int q4 = gid & 31;
            const f32x4 v = *reinterpret_cast<const f32x4*>(&lds[c][q4 << 2]);
            __builtin_nontemporal_store(v, reinterpret_cast<f32x4*>(
                out + outb + (size_t)c * m + (q4 << 2)));
        }
    }
}

extern "C" void kernel_launch(void* const* d_in, const int* in_sizes, int n_in,
                              void* d_out, int out_size, void* d_ws, size_t ws_size,
                              hipStream_t stream) {
    // inputs: y_patch (m,64) f32 [only m used], yd_patch (m,f) f32,
    //         idx_k (1,m,K) staged as int32 (absmax 0 in R2/R3/R6/R7)
    const float* yd = (const float*)d_in[1];
    const int* idx = (const int*)d_in[2];
    float* out = (float*)d_out;

    const int m = in_sizes[0] / 64;
    const int f = in_sizes[1] / m;
    const int k = in_sizes[2] / m;

    const int tiles_per_j = (m / QT) * (f / CT);   // 1024
    const int ntiles = tiles_per_j * k;            // 8192
    dim3 grid(ntiles / TPB);                       // 2048 persistent blocks
    hipLaunchKernelGGL(gather_transpose_kernel, grid, dim3(THREADS), 0,
                       stream, yd, idx, out, m, f, k, tiles_per_j);
}